// Round 10
// baseline (77.601 us; speedup 1.0000x reference)
//
#include <hip/hip_runtime.h>

// Qatten forward:
//   M[h,u,s] = sum_e W_key[h,e,u]*W_sel[h,e,s]        (kprep, LDS-tiled)
//   panel row p (400 rows, bf16, K-tile-blocked in Wp[kt][p][32]):
//     p = h*64+u (u<64): M[h,u,:];  256+h: M[h,64,:];  264+e: Wv1[e,:];
//     392+h: Wh[h,:];  260-263,396-399: zero
//   kmain (256 thr, 4 waves, BM=32, 1024 blocks, ~3 blocks/CU): C = states x
//     panel^T, 16x16x32 bf16 MFMA intrinsic. Full A-tile (32x512 bf16 = 32KB)
//     staged once; barrier-free K-loop (B direct from L2 panel); epilogue x
//     read from the LDS A-tile before the Ctile spill overwrites it.
//     Small acc (2x7 f32x4 = 56 regs) -> 12 waves/CU hide load latency.

typedef unsigned short u16;
typedef unsigned int u32;
typedef float f32x4 __attribute__((ext_vector_type(4)));
typedef short s16x8 __attribute__((ext_vector_type(8)));
typedef unsigned int u32x4 __attribute__((ext_vector_type(4)));
typedef unsigned int u32x2 __attribute__((ext_vector_type(2)));

#define NEGV -99999999.0f
#define CSTRIDE 424   // u16; 212 words = 20 mod 32 -> adjacent rows offset banks

__device__ __forceinline__ u16 f2bf(float f) {
  union { float f; u32 u; } v; v.f = f;
  u32 r = v.u + 0x7fffu + ((v.u >> 16) & 1u);
  return (u16)(r >> 16);
}
__device__ __forceinline__ float bfl(u32 w) { union { u32 u; float f; } v; v.u = w << 16; return v.f; }
__device__ __forceinline__ float bfh(u32 w) { union { u32 u; float f; } v; v.u = w & 0xffff0000u; return v.f; }

// panel element (row p, col s) -> Wp[kt][p][s&31], plain layout
__device__ __forceinline__ void panel_store(u16* Wp, int p, int s, float v) {
  Wp[(s >> 5) * 12800 + p * 32 + (s & 31)] = f2bf(v);
}

// ---------------- kprep ------------------------------------------------------
__global__ __launch_bounds__(256) void kprep(
    const float* __restrict__ Wsel, const float* __restrict__ Wkey,
    const float* __restrict__ Wv1, const float* __restrict__ Wh,
    u16* __restrict__ Wp, float* __restrict__ accs) {
  const int bid = blockIdx.x, t = threadIdx.x;
  if (bid < 128) {
    __shared__ float wsS[2048];   // [e][16]
    __shared__ float wkS[8320];   // [e][65]
    const int h = bid >> 5, s0 = (bid & 31) << 4;
    for (int i = t; i < 2048; i += 256)
      wsS[i] = Wsel[((size_t)h * 128 + (i >> 4)) * 512 + s0 + (i & 15)];
    for (int i = t; i < 8320; i += 256)
      wkS[i] = Wkey[(size_t)h * 8320 + i];
    __syncthreads();
    {
      const int u = t >> 2, sl0 = (t & 3) << 2;
      float a0 = 0.f, a1 = 0.f, a2 = 0.f, a3 = 0.f;
      for (int e = 0; e < 128; ++e) {
        const float k = wkS[e * 65 + u];
        const float* wr = wsS + e * 16 + sl0;
        a0 = fmaf(k, wr[0], a0); a1 = fmaf(k, wr[1], a1);
        a2 = fmaf(k, wr[2], a2); a3 = fmaf(k, wr[3], a3);
      }
      const int p = h * 64 + u, s = s0 + sl0;
      panel_store(Wp, p, s, a0);     panel_store(Wp, p, s + 1, a1);
      panel_store(Wp, p, s + 2, a2); panel_store(Wp, p, s + 3, a3);
    }
    if (t < 16) {  // u = 64 row
      float a = 0.f;
      for (int e = 0; e < 128; ++e)
        a = fmaf(wkS[e * 65 + 64], wsS[e * 16 + t], a);
      panel_store(Wp, 256 + h, s0 + t, a);
    }
  } else {
    if (bid == 128 && t < 16) accs[t] = 0.f;
    for (int row = 260 + (bid - 128); row < 400; row += 8) {
      for (int s = t; s < 512; s += 256) {
        float v = 0.f;
        if (row >= 264 && row < 392) v = Wv1[(row - 264) * 512 + s];
        else if (row >= 392 && row < 396) v = Wh[(row - 392) * 512 + s];
        panel_store(Wp, row, s, v);
      }
    }
  }
}

// ---------------- kmain ------------------------------------------------------
__global__ __launch_bounds__(256, 3) void kmain(
    const float* __restrict__ states, const float* __restrict__ agent_qs,
    const int* __restrict__ actions, const u16* __restrict__ Wp,
    const float* __restrict__ bv1, const float* __restrict__ Wv2,
    const float* __restrict__ bv2, const float* __restrict__ bh,
    float* __restrict__ out, float* __restrict__ accs) {
  // LDS: A = 16 sub-tiles x [32 rows][64B] = 32768B.
  // Ctile [32][CSTRIDE] u16 (27136B) reuses the same space after the x-read.
  // red (80B) at 32768. High-water 32848B -> 3+ blocks/CU (LDS-wise).
  __shared__ __align__(16) unsigned char smem[32768 + 80];
  u16* const Ctile = (u16*)smem;
  float* const red = (float*)(smem + 32768);

  const int tid = threadIdx.x;
  const int wid = tid >> 6;
  const int lane = tid & 63;
  const int c16 = lane & 15, sq = lane >> 4;
  const int slot = sq ^ ((c16 >> 1) & 3);
  const int b0 = blockIdx.x * 32;

  // ---- stage the 32x512 A tile (bf16, swizzled sub-tiles) ----
  const int ar = tid >> 3, ac8 = tid & 7;   // row 0..31, 8B chunk 0..7
  const float* aG = states + (size_t)(b0 + ar) * 512 + ac8 * 4;
  const int aWoff = ar * 64 + (((ac8 >> 1) ^ ((ar >> 1) & 3)) << 4) + (ac8 & 1) * 8;
#pragma unroll
  for (int kt = 0; kt < 16; ++kt) {
    float4 x = *(const float4*)(aG + kt * 32);
    u32x2 w;
    w[0] = (u32)f2bf(x.x) | ((u32)f2bf(x.y) << 16);
    w[1] = (u32)f2bf(x.z) | ((u32)f2bf(x.w) << 16);
    *(u32x2*)(smem + kt * 2048 + aWoff) = w;
  }
  __syncthreads();

  const f32x4 zf = {0.f, 0.f, 0.f, 0.f};
  f32x4 acc[2][7];
#pragma unroll
  for (int r = 0; r < 2; ++r)
#pragma unroll
    for (int i = 0; i < 7; ++i) acc[r][i] = zf;

  // B: colfrag f = wid + 4i; lane reads Wp[kt][f*16+c16][sq*8..+8]
  const u16* bQ[7];
#pragma unroll
  for (int i = 0; i < 7; ++i) {
    const int f = wid + (i << 2);
    bQ[i] = Wp + ((f < 25 ? f : 0) * 16 + c16) * 32 + sq * 8;
  }

  // ---- barrier-free K loop ----
#pragma unroll
  for (int kt = 0; kt < 16; ++kt) {
    s16x8 bfr[7];
#pragma unroll
    for (int i = 0; i < 7; ++i)
      if (wid + (i << 2) < 25)
        bfr[i] = *(const s16x8*)(bQ[i] + kt * 12800);
    s16x8 af[2];
#pragma unroll
    for (int r = 0; r < 2; ++r)
      af[r] = *(const s16x8*)(smem + kt * 2048 + (r * 16 + c16) * 64 + slot * 16);
#pragma unroll
    for (int i = 0; i < 7; ++i)
      if (wid + (i << 2) < 25) {
#pragma unroll
        for (int r = 0; r < 2; ++r)
          acc[r][i] = __builtin_amdgcn_mfma_f32_16x16x32_bf16(
              af[r], bfr[i], acc[r][i], 0, 0, 0);
      }
  }

  // ---- read epilogue x from the LDS A-tile (bf16) BEFORE Ctile overwrites --
  // lane (rloc, q8), agent a: cols a*64 + q8*8 .. +7 = one 16B chunk of
  // subtile kt2 = 2a + (q8>>2), chunk ac = q8&3 (swizzled).
  const int rloc = (wid << 3) + (lane >> 3);  // 0..31
  const int q8 = lane & 7;
  u32x4 xw[8];
  {
    const int rsw = (rloc >> 1) & 3;
    const int ac = q8 & 3;
#pragma unroll
    for (int a = 0; a < 8; ++a)
      xw[a] = *(const u32x4*)(smem + (2 * a + (q8 >> 2)) * 2048 + rloc * 64 +
                              ((ac ^ rsw) << 4));
  }
  __syncthreads();  // all x-reads done; A-tile may be overwritten

  // spill acc to Ctile (bf16)
#pragma unroll
  for (int r = 0; r < 2; ++r)
#pragma unroll
    for (int i = 0; i < 7; ++i) {
      const int f = wid + (i << 2);
      if (f < 25) {
        const int col = (f << 4) + c16;
        const int rowb = (r << 4) + (sq << 2);
#pragma unroll
        for (int j = 0; j < 4; ++j)
          Ctile[(rowb + j) * CSTRIDE + col] = f2bf(acc[r][i][j]);
      }
    }
  __syncthreads();

  // ---------------- epilogue: 8-lane group per row ----------------
  const int b = b0 + rloc;
  const u16* crow = Ctile + rloc * CSTRIDE;

  float m[4][8];
#pragma unroll
  for (int h = 0; h < 4; ++h) {
    u32x4 w = *(const u32x4*)(crow + h * 64 + q8 * 8);
#pragma unroll
    for (int k = 0; k < 4; ++k) {
      m[h][2 * k] = bfl(w[k]); m[h][2 * k + 1] = bfh(w[k]);
    }
  }

  float lp[4][8];
#pragma unroll
  for (int h = 0; h < 4; ++h)
#pragma unroll
    for (int a = 0; a < 8; ++a) lp[h][a] = 0.f;

#pragma unroll
  for (int a = 0; a < 8; ++a) {
    float xv[8];
#pragma unroll
    for (int k = 0; k < 4; ++k) {
      xv[2 * k] = bfl(xw[a][k]); xv[2 * k + 1] = bfh(xw[a][k]);
    }
#pragma unroll
    for (int h = 0; h < 4; ++h) {
      float s = 0.f;
#pragma unroll
      for (int j = 0; j < 8; ++j) s = fmaf(m[h][j], xv[j], s);
      lp[h][a] = s;
    }
  }
#pragma unroll
  for (int h = 0; h < 4; ++h)
#pragma unroll
    for (int a = 0; a < 8; ++a) {
      float v = lp[h][a];
      v += __shfl_xor(v, 1, 64);
      v += __shfl_xor(v, 2, 64);
      v += __shfl_xor(v, 4, 64);
      lp[h][a] = v;
    }
  // u=64 term (agent_qs)
  float4 q0 = *(const float4*)(agent_qs + (size_t)b * 8);
  float4 q1 = *(const float4*)(agent_qs + (size_t)b * 8 + 4);
  float qv[8] = {q0.x, q0.y, q0.z, q0.w, q1.x, q1.y, q1.z, q1.w};
  u32x2 w64 = *(const u32x2*)(crow + 256);
  float m64[4] = {bfl(w64[0]), bfh(w64[0]), bfl(w64[1]), bfh(w64[1])};
#pragma unroll
  for (int h = 0; h < 4; ++h)
#pragma unroll
    for (int a = 0; a < 8; ++a) lp[h][a] = fmaf(m64[h], qv[a], lp[h][a]);

  float magp = 0.f;
  if (q8 == 0) {
#pragma unroll
    for (int h = 0; h < 4; ++h)
#pragma unroll
      for (int a = 0; a < 8; ++a) magp = fmaf(lp[h][a], lp[h][a], magp);
  }
  // v partial: 16 e per lane
  float bvv[16], wvv[16], cv[16];
#pragma unroll
  for (int g = 0; g < 4; ++g) {
    *(float4*)(bvv + g * 4) = *(const float4*)(bv1 + q8 * 16 + g * 4);
    *(float4*)(wvv + g * 4) = *(const float4*)(Wv2 + q8 * 16 + g * 4);
  }
#pragma unroll
  for (int g = 0; g < 2; ++g) {
    u32x4 wv = *(const u32x4*)(crow + 264 + q8 * 16 + g * 8);
#pragma unroll
    for (int k = 0; k < 4; ++k) {
      cv[g * 8 + 2 * k] = bfl(wv[k]); cv[g * 8 + 2 * k + 1] = bfh(wv[k]);
    }
  }
  float vp = 0.f;
#pragma unroll
  for (int e2 = 0; e2 < 16; ++e2)
    vp = fmaf(fmaxf(cv[e2] + bvv[e2], 0.f), wvv[e2], vp);
  vp += __shfl_xor(vp, 1, 64);
  vp += __shfl_xor(vp, 2, 64);
  vp += __shfl_xor(vp, 4, 64);

  int av[8];
  const int* ap = actions + (size_t)b * 8;
#pragma unroll
  for (int a = 0; a < 8; ++a) av[a] = ap[a];

  u32x2 ww = *(const u32x2*)(crow + 392);
  float whr[4] = {bfl(ww[0]), bfh(ww[0]), bfl(ww[1]), bfh(ww[1])};
  float4 bh4 = *(const float4*)(bh);
  float bhv[4] = {bh4.x, bh4.y, bh4.z, bh4.w};

  const float scale = 0.088388347648318447f;  // 1/sqrt(128)
  float att[8];
#pragma unroll
  for (int a = 0; a < 8; ++a) att[a] = 0.f;
  float entp[4];
#pragma unroll
  for (int h = 0; h < 4; ++h) {
    float whv = fabsf(whr[h] + bhv[h]);
    float sc[8];
#pragma unroll
    for (int a = 0; a < 8; ++a)
      sc[a] = (av[a] == 0) ? NEGV : lp[h][a] * scale;
    float mx = sc[0];
#pragma unroll
    for (int a = 1; a < 8; ++a) mx = fmaxf(mx, sc[a]);
    float ex[8];
    float sum = 0.f;
#pragma unroll
    for (int a = 0; a < 8; ++a) { ex[a] = __expf(sc[a] - mx); sum += ex[a]; }
    float inv = 1.f / sum;
    float ent = 0.f;
#pragma unroll
    for (int a = 0; a < 8; ++a) {
      float w = ex[a] * inv;
      att[a] = fmaf(w, whv, att[a]);
      ent = fmaf(w, __logf(w + 1e-8f), ent);
    }
    entp[h] = ent;
  }

  if (q8 == 0) {
    float4 o0 = {att[0], att[1], att[2], att[3]};
    float4 o1 = {att[4], att[5], att[6], att[7]};
    *(float4*)(out + (size_t)b * 8) = o0;
    *(float4*)(out + (size_t)b * 8 + 4) = o1;
    out[262144 + b] = vp + bv2[0];
  }

  float r0 = magp;
  float r1 = (q8 == 0) ? entp[0] : 0.f;
  float r2 = (q8 == 0) ? entp[1] : 0.f;
  float r3 = (q8 == 0) ? entp[2] : 0.f;
  float r4 = (q8 == 0) ? entp[3] : 0.f;
#pragma unroll
  for (int off = 1; off < 64; off <<= 1) {
    r0 += __shfl_xor(r0, off, 64);
    r1 += __shfl_xor(r1, off, 64);
    r2 += __shfl_xor(r2, off, 64);
    r3 += __shfl_xor(r3, off, 64);
    r4 += __shfl_xor(r4, off, 64);
  }
  if (lane == 0) {
    red[wid * 5 + 0] = r0; red[wid * 5 + 1] = r1; red[wid * 5 + 2] = r2;
    red[wid * 5 + 3] = r3; red[wid * 5 + 4] = r4;
  }
  __syncthreads();
  if (tid < 5) {
    float s = red[tid] + red[5 + tid] + red[10 + tid] + red[15 + tid];
    atomicAdd(&accs[tid], s);
  }
  __syncthreads();  // block's atomics retired before counting
  if (tid == 0) {
    u32* cnt = (u32*)(accs + 8);
    if (atomicAdd(cnt, 1u) == 1023u) {  // last block finalizes
      float a0 = atomicAdd(&accs[0], 0.f);
      float a1 = atomicAdd(&accs[1], 0.f);
      float a2 = atomicAdd(&accs[2], 0.f);
      float a3 = atomicAdd(&accs[3], 0.f);
      float a4 = atomicAdd(&accs[4], 0.f);
      out[294912] = 0.001f * a0 * (1.0f / 262144.0f);
      out[294913] = -a1 * (1.0f / 32768.0f);
      out[294914] = -a2 * (1.0f / 32768.0f);
      out[294915] = -a3 * (1.0f / 32768.0f);
      out[294916] = -a4 * (1.0f / 32768.0f);
    }
  }
}

extern "C" void kernel_launch(void* const* d_in, const int* in_sizes, int n_in,
                              void* d_out, int out_size, void* d_ws, size_t ws_size,
                              hipStream_t stream) {
  const float* agent_qs = (const float*)d_in[0];
  const float* states   = (const float*)d_in[1];
  const int*   actions  = (const int*)d_in[2];
  const float* Wsel = (const float*)d_in[3];
  const float* Wkey = (const float*)d_in[4];
  const float* Wv1  = (const float*)d_in[5];
  const float* bv1  = (const float*)d_in[6];
  const float* Wv2  = (const float*)d_in[7];
  const float* bv2  = (const float*)d_in[8];
  const float* Wh   = (const float*)d_in[9];
  const float* bh   = (const float*)d_in[10];
  float* out = (float*)d_out;
  float* accs = (float*)d_ws;                    // 16 floats (incl. counter)
  u16* Wp = (u16*)((char*)d_ws + 64);            // 16 tiles x 400 x 32 bf16

  hipLaunchKernelGGL(kprep, dim3(136), dim3(256), 0, stream,
                     Wsel, Wkey, Wv1, Wh, Wp, accs);
  hipLaunchKernelGGL(kmain, dim3(1024), dim3(256), 0, stream,
                     states, agent_qs, actions, Wp, bv1, Wv2, bv2, bh, out, accs);
}

// Round 11
// 64.090 us; speedup vs baseline: 1.2108x; 1.2108x over previous
//
#include <hip/hip_runtime.h>

// Qatten forward:
//   M[h,u,s] = sum_e W_key[h,e,u]*W_sel[h,e,s]        (kprep, LDS-tiled)
//   panel: 448 rows (400 used + 48 zero pad), bf16, K-tile-blocked AND
//   chunk-XOR-swizzled in Wp[kt][p][32] (R3-verified image):
//     p = h*64+u (u<64): M[h,u,:];  256+h: M[h,64,:];  264+e: Wv1[e,:];
//     392+h: Wh[h,:];  else zero
//   kmain (256 thr, 4 waves, BM=64): C = states x panel^T, 16x16x32 bf16
//     MFMA intrinsic. 2-phase pipeline with COUNTED vmcnt (T3/T4): all
//     staging is global_load_lds (B bf16 swizzled-source; A fp32 with
//     per-lane swizzled source per m173), exactly 9 gld_lds per wave per kt
//     -> s_waitcnt vmcnt(9) + raw s_barrier keeps next tile's loads in
//     flight across the barrier. computeT reads LDS only (no VMEM).
//     A converted fp32->bf16 post-LDS with the same f2bf (bit-identical
//     MFMA inputs to R3/R8). Epilogue: R8's verified 4-lane-group version.

typedef unsigned short u16;
typedef unsigned int u32;
typedef float f32x4 __attribute__((ext_vector_type(4)));
typedef short s16x8 __attribute__((ext_vector_type(8)));
typedef unsigned int u32x4 __attribute__((ext_vector_type(4)));
typedef unsigned int u32x2 __attribute__((ext_vector_type(2)));
typedef __attribute__((address_space(1))) const u32 gu32;
typedef __attribute__((address_space(3))) u32 lu32;

#define NEGV -99999999.0f
#define CSTRIDE 424     // u16; verified low-conflict epilogue stride (R8)
#define PKTB 28672      // bytes per panel K-tile: 448 rows x 64B

__device__ __forceinline__ u16 f2bf(float f) {
  union { float f; u32 u; } v; v.f = f;
  u32 r = v.u + 0x7fffu + ((v.u >> 16) & 1u);
  return (u16)(r >> 16);
}
__device__ __forceinline__ float bfl(u32 w) { union { u32 u; float f; } v; v.u = w << 16; return v.f; }
__device__ __forceinline__ float bfh(u32 w) { union { u32 u; float f; } v; v.u = w & 0xffff0000u; return v.f; }

// panel element (row p, col s) -> K-tiled + chunk-XOR-swizzled position
__device__ __forceinline__ void panel_store(u16* Wp, int p, int s, float v) {
  const int kt = s >> 5, c = (s >> 3) & 3, j = s & 7;
  Wp[kt * 14336 + p * 32 + ((c ^ ((p >> 1) & 3)) << 3) + j] = f2bf(v);
}

// ---------------- kprep ------------------------------------------------------
__global__ __launch_bounds__(256) void kprep(
    const float* __restrict__ Wsel, const float* __restrict__ Wkey,
    const float* __restrict__ Wv1, const float* __restrict__ Wh,
    u16* __restrict__ Wp, float* __restrict__ accs) {
  const int bid = blockIdx.x, t = threadIdx.x;
  if (bid < 128) {
    __shared__ float wsS[2048];   // [e][16]
    __shared__ float wkS[8320];   // [e][65]
    const int h = bid >> 5, s0 = (bid & 31) << 4;
    for (int i = t; i < 2048; i += 256)
      wsS[i] = Wsel[((size_t)h * 128 + (i >> 4)) * 512 + s0 + (i & 15)];
    for (int i = t; i < 8320; i += 256)
      wkS[i] = Wkey[(size_t)h * 8320 + i];
    __syncthreads();
    {
      const int u = t >> 2, sl0 = (t & 3) << 2;
      float a0 = 0.f, a1 = 0.f, a2 = 0.f, a3 = 0.f;
      for (int e = 0; e < 128; ++e) {
        const float k = wkS[e * 65 + u];
        const float* wr = wsS + e * 16 + sl0;
        a0 = fmaf(k, wr[0], a0); a1 = fmaf(k, wr[1], a1);
        a2 = fmaf(k, wr[2], a2); a3 = fmaf(k, wr[3], a3);
      }
      const int p = h * 64 + u, s = s0 + sl0;
      panel_store(Wp, p, s, a0);     panel_store(Wp, p, s + 1, a1);
      panel_store(Wp, p, s + 2, a2); panel_store(Wp, p, s + 3, a3);
    }
    if (t < 16) {  // u = 64 row
      float a = 0.f;
      for (int e = 0; e < 128; ++e)
        a = fmaf(wkS[e * 65 + 64], wsS[e * 16 + t], a);
      panel_store(Wp, 256 + h, s0 + t, a);
    }
  } else {
    if (bid == 128 && t < 16) accs[t] = 0.f;
    for (int row = 260 + (bid - 128); row < 448; row += 8) {
      for (int s = t; s < 512; s += 256) {
        float v = 0.f;
        if (row >= 264 && row < 392) v = Wv1[(row - 264) * 512 + s];
        else if (row >= 392 && row < 396) v = Wh[(row - 392) * 512 + s];
        panel_store(Wp, row, s, v);
      }
    }
  }
}

// ---------------- kmain ------------------------------------------------------
// per kt per wave: 7 B-gld_lds (1KB each, 28 chunks over 4 waves) +
// 2 A-gld_lds (fp32, per-lane swizzled source) = 9 VMEM ops exactly.
__device__ __forceinline__ void stage_tile(
    unsigned char* bufB, unsigned char* bufA, const char* wpB,
    const float* pA0, const float* pA1, int wid) {
#pragma unroll
  for (int i = 0; i < 7; ++i) {
    const int c = wid + (i << 2);
    __builtin_amdgcn_global_load_lds((gu32*)(wpB + c * 1024),
                                     (lu32*)(bufB + c * 1024), 16, 0, 0);
  }
  __builtin_amdgcn_global_load_lds((gu32*)pA0, (lu32*)(bufA + wid * 1024), 16, 0, 0);
  __builtin_amdgcn_global_load_lds((gu32*)pA1, (lu32*)(bufA + (wid + 4) * 1024), 16, 0, 0);
}

__device__ __forceinline__ void computeT(const unsigned char* bufA,
                                         const unsigned char* bufB,
                                         int wid, int c16, int sq,
                                         f32x4 acc[4][7]) {
  const int slotB = sq ^ ((c16 >> 1) & 3);
  const int swz = c16 & 7;
  s16x8 af[4];
#pragma unroll
  for (int r = 0; r < 4; ++r) {
    const unsigned char* rb = bufA + (r * 16 + c16) * 128;
    f32x4 wa = *(const f32x4*)(rb + (((2 * sq) ^ swz) << 4));
    f32x4 wb = *(const f32x4*)(rb + (((2 * sq + 1) ^ swz) << 4));
    af[r][0] = (short)f2bf(wa[0]); af[r][1] = (short)f2bf(wa[1]);
    af[r][2] = (short)f2bf(wa[2]); af[r][3] = (short)f2bf(wa[3]);
    af[r][4] = (short)f2bf(wb[0]); af[r][5] = (short)f2bf(wb[1]);
    af[r][6] = (short)f2bf(wb[2]); af[r][7] = (short)f2bf(wb[3]);
  }
#pragma unroll
  for (int i = 0; i < 7; ++i) {
    const int f = wid + (i << 2);
    if (f < 25) {
      s16x8 bfr = *(const s16x8*)(bufB + (f * 16 + c16) * 64 + slotB * 16);
#pragma unroll
      for (int r = 0; r < 4; ++r)
        acc[r][i] = __builtin_amdgcn_mfma_f32_16x16x32_bf16(
            af[r], bfr, acc[r][i], 0, 0, 0);
    }
  }
}

__global__ __launch_bounds__(256, 2) void kmain(
    const float* __restrict__ states, const float* __restrict__ agent_qs,
    const int* __restrict__ actions, const u16* __restrict__ Wp,
    const float* __restrict__ bv1, const float* __restrict__ Wv2,
    const float* __restrict__ bv2, const float* __restrict__ bh,
    float* __restrict__ out, float* __restrict__ accs) {
  // LDS: B0@0 B1@28672 (28.7KB each) | A0@57344 A1@65536 (8KB fp32 each)
  // Ctile [64][424] u16 = 54272B overlays B-region post-loop; red @73728.
  __shared__ __align__(16) unsigned char smem[73728 + 80];
  unsigned char* const B0 = smem;
  unsigned char* const B1 = smem + 28672;
  unsigned char* const A0 = smem + 57344;
  unsigned char* const A1 = smem + 65536;
  u16* const Ctile = (u16*)smem;
  float* const red = (float*)(smem + 73728);

  const int tid = threadIdx.x;
  const int wid = tid >> 6;
  const int lane = tid & 63;
  const int c16 = lane & 15, sq = lane >> 4;
  const int b0 = blockIdx.x * 64;

  const f32x4 zf = {0.f, 0.f, 0.f, 0.f};
  f32x4 acc[4][7];
#pragma unroll
  for (int r = 0; r < 4; ++r)
#pragma unroll
    for (int i = 0; i < 7; ++i) acc[r][i] = zf;

  // A gld_lds source: lane l of chunk c covers LDS row 8c+(l>>3), slot l&7;
  // swizzled source chunk = (l&7)^(l>>3) (row&7 == l>>3).
  const int rowoff = lane >> 3;
  const int xslot = (lane & 7) ^ rowoff;
  const float* pA0 = states + (size_t)(b0 + 8 * wid + rowoff) * 512 + xslot * 4;
  const float* pA1 = pA0 + 32 * 512;
  const char* const wpB = (const char*)Wp + lane * 16;

  // ---- prologue: stage tile 0, full drain once ----
  stage_tile(B0, A0, wpB, pA0, pA1, wid);
  asm volatile("s_waitcnt vmcnt(0)" ::: "memory");
  __builtin_amdgcn_s_barrier();

  // ---- counted-vmcnt 2-phase K loop ----
  for (int kt = 0; kt < 15; ++kt) {
    unsigned char* const sbB = (kt & 1) ? B0 : B1;
    unsigned char* const sbA = (kt & 1) ? A0 : A1;
    const unsigned char* const cbB = (kt & 1) ? B1 : B0;
    const unsigned char* const cbA = (kt & 1) ? A1 : A0;
    stage_tile(sbB, sbA, wpB + (size_t)(kt + 1) * PKTB,
               pA0 + (kt + 1) * 32, pA1 + (kt + 1) * 32, wid);
    __builtin_amdgcn_sched_barrier(0);
    asm volatile("s_waitcnt vmcnt(9)" ::: "memory");  // kt's 9 landed; kt+1's fly
    __builtin_amdgcn_s_barrier();
    computeT(cbA, cbB, wid, c16, sq, acc);
    __builtin_amdgcn_sched_barrier(0);
    __builtin_amdgcn_s_barrier();   // all waves done reading cb before restage
  }
  asm volatile("s_waitcnt vmcnt(0)" ::: "memory");
  __builtin_amdgcn_s_barrier();
  computeT(A1, B1, wid, c16, sq, acc);  // kt = 15
  __syncthreads();                       // B/A region dead; Ctile may overwrite

  // spill acc to Ctile (bf16)
#pragma unroll
  for (int r = 0; r < 4; ++r)
#pragma unroll
    for (int i = 0; i < 7; ++i) {
      const int f = wid + (i << 2);
      if (f < 25) {
        const int col = (f << 4) + c16;
        const int rowb = (r << 4) + (sq << 2);
#pragma unroll
        for (int j = 0; j < 4; ++j)
          Ctile[(rowb + j) * CSTRIDE + col] = f2bf(acc[r][i][j]);
      }
    }
  __syncthreads();

  // ---------------- epilogue: 4-lane group (stride-16 lanes) per row --------
  const int rloc = (wid << 4) + c16;  // 0..63
  const int b = b0 + rloc;
  const int qt = sq;
  const u16* crow = Ctile + rloc * CSTRIDE;
  const float* srow = states + (size_t)b * 512;

  float m[4][16];
#pragma unroll
  for (int h = 0; h < 4; ++h) {
    u32x4 w0 = *(const u32x4*)(crow + h * 64 + qt * 16);
    u32x4 w1 = *(const u32x4*)(crow + h * 64 + qt * 16 + 8);
#pragma unroll
    for (int k = 0; k < 4; ++k) {
      m[h][2 * k] = bfl(w0[k]);     m[h][2 * k + 1] = bfh(w0[k]);
      m[h][8 + 2 * k] = bfl(w1[k]); m[h][8 + 2 * k + 1] = bfh(w1[k]);
    }
  }

  float lp[4][8];
#pragma unroll
  for (int h = 0; h < 4; ++h)
#pragma unroll
    for (int a = 0; a < 8; ++a) lp[h][a] = 0.f;

#pragma unroll
  for (int a = 0; a < 8; ++a) {
    const float* xp = srow + a * 64 + qt * 16;
    float4 v0 = *(const float4*)(xp);
    float4 v1 = *(const float4*)(xp + 4);
    float4 v2 = *(const float4*)(xp + 8);
    float4 v3 = *(const float4*)(xp + 12);
    float xv[16] = {v0.x, v0.y, v0.z, v0.w, v1.x, v1.y, v1.z, v1.w,
                    v2.x, v2.y, v2.z, v2.w, v3.x, v3.y, v3.z, v3.w};
#pragma unroll
    for (int h = 0; h < 4; ++h) {
      float s = 0.f;
#pragma unroll
      for (int t2 = 0; t2 < 16; ++t2) s = fmaf(m[h][t2], xv[t2], s);
      lp[h][a] += s;
    }
  }
#pragma unroll
  for (int h = 0; h < 4; ++h)
#pragma unroll
    for (int a = 0; a < 8; ++a) {
      float v = lp[h][a];
      v += __shfl_xor(v, 16, 64);
      v += __shfl_xor(v, 32, 64);
      lp[h][a] = v;
    }
  // u=64 term (agent_qs)
  float4 q0 = *(const float4*)(agent_qs + (size_t)b * 8);
  float4 q1 = *(const float4*)(agent_qs + (size_t)b * 8 + 4);
  float qv[8] = {q0.x, q0.y, q0.z, q0.w, q1.x, q1.y, q1.z, q1.w};
  u32x2 w64 = *(const u32x2*)(crow + 256);
  float m64[4] = {bfl(w64[0]), bfh(w64[0]), bfl(w64[1]), bfh(w64[1])};
#pragma unroll
  for (int h = 0; h < 4; ++h)
#pragma unroll
    for (int a = 0; a < 8; ++a) lp[h][a] = fmaf(m64[h], qv[a], lp[h][a]);

  float magp = 0.f;
  if (qt == 0) {
#pragma unroll
    for (int h = 0; h < 4; ++h)
#pragma unroll
      for (int a = 0; a < 8; ++a) magp = fmaf(lp[h][a], lp[h][a], magp);
  }
  // v partial: 32 e per lane-quarter
  float bvv[32], wvv[32], cv[32];
#pragma unroll
  for (int g = 0; g < 8; ++g) {
    *(float4*)(bvv + g * 4) = *(const float4*)(bv1 + qt * 32 + g * 4);
    *(float4*)(wvv + g * 4) = *(const float4*)(Wv2 + qt * 32 + g * 4);
  }
#pragma unroll
  for (int g = 0; g < 4; ++g) {
    u32x4 wv = *(const u32x4*)(crow + 264 + qt * 32 + g * 8);
#pragma unroll
    for (int k = 0; k < 4; ++k) {
      cv[g * 8 + 2 * k] = bfl(wv[k]); cv[g * 8 + 2 * k + 1] = bfh(wv[k]);
    }
  }
  float vp = 0.f;
#pragma unroll
  for (int e2 = 0; e2 < 32; ++e2)
    vp = fmaf(fmaxf(cv[e2] + bvv[e2], 0.f), wvv[e2], vp);
  vp += __shfl_xor(vp, 16, 64);
  vp += __shfl_xor(vp, 32, 64);

  int av[8];
  const int* ap = actions + (size_t)b * 8;
#pragma unroll
  for (int a = 0; a < 8; ++a) av[a] = ap[a];

  u32x2 ww = *(const u32x2*)(crow + 392);
  float whr[4] = {bfl(ww[0]), bfh(ww[0]), bfl(ww[1]), bfh(ww[1])};
  float4 bh4 = *(const float4*)(bh);
  float bhv[4] = {bh4.x, bh4.y, bh4.z, bh4.w};

  const float scale = 0.088388347648318447f;  // 1/sqrt(128)
  float att[8];
#pragma unroll
  for (int a = 0; a < 8; ++a) att[a] = 0.f;
  float entp[4];
#pragma unroll
  for (int h = 0; h < 4; ++h) {
    float whv = fabsf(whr[h] + bhv[h]);
    float sc[8];
#pragma unroll
    for (int a = 0; a < 8; ++a)
      sc[a] = (av[a] == 0) ? NEGV : lp[h][a] * scale;
    float mx = sc[0];
#pragma unroll
    for (int a = 1; a < 8; ++a) mx = fmaxf(mx, sc[a]);
    float ex[8];
    float sum = 0.f;
#pragma unroll
    for (int a = 0; a < 8; ++a) { ex[a] = __expf(sc[a] - mx); sum += ex[a]; }
    float inv = 1.f / sum;
    float ent = 0.f;
#pragma unroll
    for (int a = 0; a < 8; ++a) {
      float w = ex[a] * inv;
      att[a] = fmaf(w, whv, att[a]);
      ent = fmaf(w, __logf(w + 1e-8f), ent);
    }
    entp[h] = ent;
  }

  if (qt == 0) {
    float4 o0 = {att[0], att[1], att[2], att[3]};
    float4 o1 = {att[4], att[5], att[6], att[7]};
    *(float4*)(out + (size_t)b * 8) = o0;
    *(float4*)(out + (size_t)b * 8 + 4) = o1;
    out[262144 + b] = vp + bv2[0];
  }

  float r0 = magp;
  float r1 = (qt == 0) ? entp[0] : 0.f;
  float r2 = (qt == 0) ? entp[1] : 0.f;
  float r3 = (qt == 0) ? entp[2] : 0.f;
  float r4 = (qt == 0) ? entp[3] : 0.f;
#pragma unroll
  for (int off = 1; off < 64; off <<= 1) {
    r0 += __shfl_xor(r0, off, 64);
    r1 += __shfl_xor(r1, off, 64);
    r2 += __shfl_xor(r2, off, 64);
    r3 += __shfl_xor(r3, off, 64);
    r4 += __shfl_xor(r4, off, 64);
  }
  if (lane == 0) {
    red[wid * 5 + 0] = r0; red[wid * 5 + 1] = r1; red[wid * 5 + 2] = r2;
    red[wid * 5 + 3] = r3; red[wid * 5 + 4] = r4;
  }
  __syncthreads();
  if (tid < 5) {
    float s = red[tid] + red[5 + tid] + red[10 + tid] + red[15 + tid];
    atomicAdd(&accs[tid], s);
  }
  __syncthreads();  // block's atomics retired before counting
  if (tid == 0) {
    u32* cnt = (u32*)(accs + 8);
    if (atomicAdd(cnt, 1u) == 511u) {  // last block finalizes
      float a0 = atomicAdd(&accs[0], 0.f);
      float a1 = atomicAdd(&accs[1], 0.f);
      float a2 = atomicAdd(&accs[2], 0.f);
      float a3 = atomicAdd(&accs[3], 0.f);
      float a4 = atomicAdd(&accs[4], 0.f);
      out[294912] = 0.001f * a0 * (1.0f / 262144.0f);
      out[294913] = -a1 * (1.0f / 32768.0f);
      out[294914] = -a2 * (1.0f / 32768.0f);
      out[294915] = -a3 * (1.0f / 32768.0f);
      out[294916] = -a4 * (1.0f / 32768.0f);
    }
  }
}

extern "C" void kernel_launch(void* const* d_in, const int* in_sizes, int n_in,
                              void* d_out, int out_size, void* d_ws, size_t ws_size,
                              hipStream_t stream) {
  const float* agent_qs = (const float*)d_in[0];
  const float* states   = (const float*)d_in[1];
  const int*   actions  = (const int*)d_in[2];
  const float* Wsel = (const float*)d_in[3];
  const float* Wkey = (const float*)d_in[4];
  const float* Wv1  = (const float*)d_in[5];
  const float* bv1  = (const float*)d_in[6];
  const float* Wv2  = (const float*)d_in[7];
  const float* bv2  = (const float*)d_in[8];
  const float* Wh   = (const float*)d_in[9];
  const float* bh   = (const float*)d_in[10];
  float* out = (float*)d_out;
  float* accs = (float*)d_ws;                    // 16 floats (incl. counter)
  u16* Wp = (u16*)((char*)d_ws + 64);            // 16 tiles x 448 x 32 bf16

  hipLaunchKernelGGL(kprep, dim3(136), dim3(256), 0, stream,
                     Wsel, Wkey, Wv1, Wh, Wp, accs);
  hipLaunchKernelGGL(kmain, dim3(512), dim3(256), 0, stream,
                     states, agent_qs, actions, Wp, bv1, Wv2, bv2, bh, out, accs);
}